// Round 4
// baseline (69.064 us; speedup 1.0000x reference)
//
#include <hip/hip_runtime.h>

// Sinkhorn loss, fully fused, MFMA edition v4 — single dispatch.
// One block per batch (b=16), n=48x48=2304, 5 iterations.
// Block 0 finishes the mean via flag-spin on d_ws (poisoned 0xAA by the
// harness each call => flags are self-initializing, no memset dispatch).
//
// S = T @ W @ T per half-iteration (T = separable Gaussian table, symmetric),
// as two 48x48x48 stages of nine 16x16 MFMA tiles (one per wave, 9 waves).
//  - T / TD A-fragments live in REGISTERS (hi/lo bf16 split, fp32-grade).
//  - W / P stored bf16-RNE in LDS; B-fragment reads only.
//  - u/v update in MFMA C/D layout by the owning lane; 2 barriers/half-iter.
//  - 100*EPS == 1  =>  w' = w * mu / (w*S + 1e-6): no log/exp in the loop.

#define TPB 576      // 9 waves = 9 MFMA tiles of 16x16 = 48x48
#define STRIDE 72    // shorts per LDS matrix row (144 B, 16B-aligned frags)
#define FLAG_MAGIC 0x5CA1AB1Eu

typedef __attribute__((ext_vector_type(8))) short short8;
typedef __attribute__((ext_vector_type(4))) float f32x4;

__device__ __forceinline__ void splitb(float x, short& hi, short& lo) {
    union { float f; unsigned u; } a, h;
    a.f = x;
    h.u = a.u & 0xffff0000u;          // truncate; lo captures residual
    hi  = (short)(h.u >> 16);
    union { float f; unsigned u; } l;
    l.f = x - h.f;
    lo  = (short)(l.u >> 16);
}

__device__ __forceinline__ short bf16rne(float x) {
    union { float f; unsigned u; } a;
    a.f = x;
    unsigned r = a.u + 0x7fffu + ((a.u >> 16) & 1u);
    return (short)(r >> 16);
}

__device__ __forceinline__ f32x4 mm16(short8 a, short8 b, f32x4 c) {
    return __builtin_amdgcn_mfma_f32_16x16x32_bf16(a, b, c, 0, 0, 0);
}

__global__ __launch_bounds__(TPB) void sinkhorn_kernel(const float* __restrict__ y,
                                                       const float* __restrict__ yt,
                                                       unsigned* __restrict__ flags,
                                                       float* __restrict__ parts,
                                                       float* __restrict__ out)
{
    __shared__ __align__(16) short sW[48 * STRIDE];   // exp(./eps), bf16
    __shared__ __align__(16) short sP[48 * STRIDE];   // stage-1 out, bf16
    __shared__ __align__(16) short sP2[48 * STRIDE];  // final-cost second buf
    __shared__ float red[32];

    const int t    = threadIdx.x;
    const int b    = blockIdx.x;
    const int lane = t & 63;
    const int wid  = t >> 6;            // wave id 0..8
    const int tr   = wid / 3;           // tile row
    const int tc   = wid - tr * 3;      // tile col
    const int n15  = lane & 15;
    const int quad = lane >> 4;
    const int kq   = quad * 8;
    const int aRow = tr * 16 + n15;              // A-frag row (m)
    const int bBase = (tc * 16 + n15) * STRIDE;  // B-frag row base (n)
    const int prBase = tr * 16 + quad * 4;       // C/D row base
    const int pn     = tc * 16 + n15;            // C/D col
    const int wAddr  = prBase * STRIDE + pn;     // scatter-write base (shorts)

    // ---- issue global input loads FIRST (hide ~900cyc cold-miss latency
    //      under the T-table transcendental init below) ----
    float yv_[4], ytv_[4];
#pragma unroll
    for (int rg = 0; rg < 4; ++rg) {
        int e = (prBase + rg) * 48 + pn;
        yv_[rg]  = y [b * 2304 + e];
        ytv_[rg] = yt[b * 2304 + e];
    }

    // ---- T / TD A-fragments in registers (hi/lo bf16 split) ----
    // A[m][k]; lane holds k = kq..kq+7 (frag0) and kq+32..kq+39 (frag1).
    short8 Th0, Th1, Tl0, Tl1, Dh0, Dh1, Dl0, Dl1;
    {
        const float gm = (float)aRow / 48.0f;
#pragma unroll
        for (int kk = 0; kk < 8; ++kk) {
            int k0 = kq + kk;
            float d = gm - (float)k0 / 48.0f;
            float dsq = d * d;
            float e = __expf(-100.0f * dsq);
            short h, l;
            splitb(e, h, l);        Th0[kk] = h; Tl0[kk] = l;
            splitb(e * dsq, h, l);  Dh0[kk] = h; Dl0[kk] = l;
            int k1 = k0 + 32;
            if (k1 < 48) {
                float d1 = gm - (float)k1 / 48.0f;
                float q1 = d1 * d1;
                float e1 = __expf(-100.0f * q1);
                splitb(e1, h, l);       Th1[kk] = h; Tl1[kk] = l;
                splitb(e1 * q1, h, l);  Dh1[kk] = h; Dl1[kk] = l;
            } else {
                Th1[kk] = 0; Tl1[kk] = 0; Dh1[kk] = 0; Dl1[kk] = 0;
            }
        }
    }

    // ---- init LDS: W = 1.0 (bf16) in body, 0 in K-pad; P/P2 pads zeroed ----
    for (int i = t; i < 48 * STRIDE; i += TPB) {
        int col = i - (i / STRIDE) * STRIDE;
        sW[i]  = (col < 48) ? (short)0x3F80 : (short)0;
        sP[i]  = 0;
        sP2[i] = 0;
    }

    // ---- masses in C/D layout: lane owns elements (prBase+rg, pn) ----
    float mx[4], my[4];
#pragma unroll
    for (int rg = 0; rg < 4; ++rg) {
        mx[rg] = fminf(fmaxf(yv_[rg],  0.f), 1e9f) + 1e-9f;
        my[rg] = fminf(fmaxf(ytv_[rg], 0.f), 1e9f) + 1e-9f;
    }
    float sx = mx[0] + mx[1] + mx[2] + mx[3];
    float sy = my[0] + my[1] + my[2] + my[3];
#pragma unroll
    for (int off = 32; off > 0; off >>= 1) {
        sx += __shfl_down(sx, off);
        sy += __shfl_down(sy, off);
    }
    if (lane == 0) { red[wid] = sx; red[16 + wid] = sy; }
    __syncthreads();   // also covers the sW/sP init above
    float ax = 0.f, ay = 0.f;
#pragma unroll
    for (int w = 0; w < TPB / 64; ++w) { ax += red[w]; ay += red[16 + w]; }
    const float rsx = 1.0f / ax, rsy = 1.0f / ay;

    float mu_[4], nu_[4];
#pragma unroll
    for (int c = 0; c < 4; ++c) { mu_[c] = mx[c] * rsx; nu_[c] = my[c] * rsy; }

    float wu_[4] = {1, 1, 1, 1}, wv_[4] = {1, 1, 1, 1};  // exp(u/eps), exp(v/eps)

    const f32x4 zz = {0.f, 0.f, 0.f, 0.f};

    // ---- 10 half-iterations: u-update (even) / v-update (odd) ----
    for (int half = 0; half < 10; ++half) {
        // stage 1: P = T-tile @ W  (B-frags read sW row-major)
        {
            short8 b0 = *(const short8*)(sW + bBase + kq);
            short8 b1 = *(const short8*)(sW + bBase + kq + 32);
            f32x4 x  = mm16(Th0, b0, zz);
            f32x4 yy = mm16(Th1, b1, zz);
            x  = mm16(Tl0, b0, x);
            yy = mm16(Tl1, b1, yy);
            f32x4 p = x + yy;
#pragma unroll
            for (int rg = 0; rg < 4; ++rg)
                sP[wAddr + rg * STRIDE] = bf16rne(p[rg]);
        }
        __syncthreads();
        // stage 2: S = T-tile @ P; update state in C/D layout; write new W
        {
            short8 b0 = *(const short8*)(sP + bBase + kq);
            short8 b1 = *(const short8*)(sP + bBase + kq + 32);
            f32x4 x  = mm16(Th0, b0, zz);
            f32x4 yy = mm16(Th1, b1, zz);
            x  = mm16(Tl0, b0, x);
            yy = mm16(Tl1, b1, yy);
            f32x4 S = x + yy;
            float* wc       = ((half & 1) == 0) ? wu_ : wv_;
            const float* m_ = ((half & 1) == 0) ? mu_ : nu_;
#pragma unroll
            for (int c = 0; c < 4; ++c) {
                // 100*eps == 1:  w' = e^{u'/eps} = w * mu / (w*S + 1e-6)
                wc[c] = wc[c] * m_[c] / (wc[c] * S[c] + 1e-6f);
                sW[wAddr + c * STRIDE] = bf16rne(wc[c]);
            }
        }
        __syncthreads();
    }

    // ---- final cost: sum_i wu_i * (TD@(T@Wv) + T@(TD@Wv))_i ----
    {
        short8 b0 = *(const short8*)(sW + bBase + kq);
        short8 b1 = *(const short8*)(sW + bBase + kq + 32);
        f32x4 x1 = mm16(Th0, b0, zz), y1 = mm16(Th1, b1, zz);
        x1 = mm16(Tl0, b0, x1);  y1 = mm16(Tl1, b1, y1);
        f32x4 p1 = x1 + y1;                       // T @ Wv
        f32x4 x2 = mm16(Dh0, b0, zz), y2 = mm16(Dh1, b1, zz);
        x2 = mm16(Dl0, b0, x2);  y2 = mm16(Dl1, b1, y2);
        f32x4 p2 = x2 + y2;                       // TD @ Wv
#pragma unroll
        for (int rg = 0; rg < 4; ++rg) {
            sP [wAddr + rg * STRIDE] = bf16rne(p1[rg]);
            sP2[wAddr + rg * STRIDE] = bf16rne(p2[rg]);
        }
    }
    __syncthreads();
    float local;
    {
        short8 b0 = *(const short8*)(sP  + bBase + kq);
        short8 b1 = *(const short8*)(sP  + bBase + kq + 32);
        short8 c0 = *(const short8*)(sP2 + bBase + kq);
        short8 c1 = *(const short8*)(sP2 + bBase + kq + 32);
        f32x4 x  = mm16(Dh0, b0, zz), yy = mm16(Dh1, b1, zz);
        x  = mm16(Dl0, b0, x);   yy = mm16(Dl1, b1, yy);
        x  = mm16(Th0, c0, x);   yy = mm16(Th1, c1, yy);
        x  = mm16(Tl0, c0, x);   yy = mm16(Tl1, c1, yy);
        f32x4 S = x + yy;
        local = wu_[0] * S[0] + wu_[1] * S[1] + wu_[2] * S[2] + wu_[3] * S[3];
    }
#pragma unroll
    for (int off = 32; off > 0; off >>= 1) local += __shfl_down(local, off);
    if (lane == 0) red[wid] = local;
    __syncthreads();

    // ---- cross-block finish: blocks 1..15 post partial+flag; block 0 sums ----
    if (t == 0) {
        float c = 0.f;
#pragma unroll
        for (int w = 0; w < TPB / 64; ++w) c += red[w];
        if (b != 0) {
            __hip_atomic_store(&parts[b], c, __ATOMIC_RELAXED,
                               __HIP_MEMORY_SCOPE_AGENT);
            __hip_atomic_store(&flags[b], FLAG_MAGIC, __ATOMIC_RELEASE,
                               __HIP_MEMORY_SCOPE_AGENT);
        } else {
            float tot = c;
            for (int i = 1; i < 16; ++i) {
                while (__hip_atomic_load(&flags[i], __ATOMIC_ACQUIRE,
                                         __HIP_MEMORY_SCOPE_AGENT) != FLAG_MAGIC) { }
                tot += __hip_atomic_load(&parts[i], __ATOMIC_RELAXED,
                                         __HIP_MEMORY_SCOPE_AGENT);
            }
            out[0] = tot * (1.0f / 16.0f);
        }
    }
}

extern "C" void kernel_launch(void* const* d_in, const int* in_sizes, int n_in,
                              void* d_out, int out_size, void* d_ws, size_t ws_size,
                              hipStream_t stream)
{
    (void)in_sizes; (void)n_in; (void)ws_size; (void)out_size;
    const float* y  = (const float*)d_in[0];
    const float* yt = (const float*)d_in[1];
    unsigned* flags = (unsigned*)d_ws;             // ws[0..15]  (0xAA-poisoned)
    float*    parts = (float*)d_ws + 16;           // ws[16..31]
    float*    out   = (float*)d_out;

    sinkhorn_kernel<<<16, TPB, 0, stream>>>(y, yt, flags, parts, out);
}

// Round 5
// 67.281 us; speedup vs baseline: 1.0265x; 1.0265x over previous
//
#include <hip/hip_runtime.h>

// Sinkhorn loss, fully fused, MFMA edition v5 — single dispatch.
// One block per batch (b=16), n=48x48=2304, 5 iterations.
//
// v5 changes vs v4:
//  - LDS data rides the MFMA A-slot; constant T/TD fragments ride the B-slot
//    (T symmetric => same registers serve either slot). Every stage stores
//    its result TRANSPOSED, making each lane's 4 C/D elements contiguous:
//    one ds_write_b64 instead of 4 scattered ds_write_b16. Double-transpose
//    per contraction restores orientation (T@X@T commutes with transpose);
//    lane-state slots sit at fixed logical (c,r) = (tc*16+n15, tr*16+quad*4+rg),
//    so the global input loads become float4 as a bonus.
//  - Cross-block finish: block 0 polls the 15 flags IN PARALLEL (one lane
//    per flag + shuffle reduce) instead of serially (R4's regression).
//  - 100*EPS == 1  =>  w' = w * mu / (w*S + 1e-6): no log/exp in the loop.

#define TPB 576      // 9 waves = 9 MFMA tiles of 16x16 = 48x48
#define STRIDE 72    // shorts per LDS matrix row (144 B, 16B-aligned frags)
#define FLAG_MAGIC 0x5CA1AB1Eu

typedef __attribute__((ext_vector_type(8))) short short8;
typedef __attribute__((ext_vector_type(4))) short short4v;
typedef __attribute__((ext_vector_type(4))) float f32x4;

__device__ __forceinline__ void splitb(float x, short& hi, short& lo) {
    union { float f; unsigned u; } a, h;
    a.f = x;
    h.u = a.u & 0xffff0000u;          // truncate; lo captures residual
    hi  = (short)(h.u >> 16);
    union { float f; unsigned u; } l;
    l.f = x - h.f;
    lo  = (short)(l.u >> 16);
}

__device__ __forceinline__ short bf16rne(float x) {
    union { float f; unsigned u; } a;
    a.f = x;
    unsigned r = a.u + 0x7fffu + ((a.u >> 16) & 1u);
    return (short)(r >> 16);
}

__device__ __forceinline__ f32x4 mm16(short8 a, short8 b, f32x4 c) {
    return __builtin_amdgcn_mfma_f32_16x16x32_bf16(a, b, c, 0, 0, 0);
}

__global__ __launch_bounds__(TPB) void sinkhorn_kernel(const float* __restrict__ y,
                                                       const float* __restrict__ yt,
                                                       unsigned* __restrict__ flags,
                                                       float* __restrict__ parts,
                                                       float* __restrict__ out)
{
    __shared__ __align__(16) short sW [48 * STRIDE];  // current W (row-major)
    __shared__ __align__(16) short sP [48 * STRIDE];  // stage-1 out (transposed)
    __shared__ __align__(16) short sP2[48 * STRIDE];  // final-cost second buf
    __shared__ float red[32];

    const int t    = threadIdx.x;
    const int b    = blockIdx.x;
    const int lane = t & 63;
    const int wid  = t >> 6;            // wave id 0..8
    const int tr   = wid / 3;           // tile row
    const int tc   = wid - tr * 3;      // tile col
    const int n15  = lane & 15;
    const int quad = lane >> 4;
    const int kq   = quad * 8;
    const int r0   = tr * 16 + quad * 4;   // C/D row base
    const int c    = tc * 16 + n15;        // C/D col; also T-register row
    const int aBase  = (tr * 16 + n15) * STRIDE;      // A-frag row base (LDS)
    const int stBase = c * STRIDE + r0;               // transpose-store base
    // lane's elementwise slots: logical (c, r0+rg), rg = 0..3

    // ---- global input loads FIRST (float4; hide cold-miss under exp init) ----
    const f32x4 y4  = *(const f32x4*)(y  + b * 2304 + c * 48 + r0);
    const f32x4 yt4 = *(const f32x4*)(yt + b * 2304 + c * 48 + r0);

    // ---- T / TD register fragments, row c, hi/lo bf16 split (B-slot use) ----
    short8 Th0, Th1, Tl0, Tl1, Dh0, Dh1, Dl0, Dl1;
    {
        const float gm = (float)c / 48.0f;
#pragma unroll
        for (int kk = 0; kk < 8; ++kk) {
            int k0 = kq + kk;
            float d = gm - (float)k0 / 48.0f;
            float dsq = d * d;
            float e = __expf(-100.0f * dsq);
            short h, l;
            splitb(e, h, l);        Th0[kk] = h; Tl0[kk] = l;
            splitb(e * dsq, h, l);  Dh0[kk] = h; Dl0[kk] = l;
            int k1 = k0 + 32;
            if (k1 < 48) {
                float d1 = gm - (float)k1 / 48.0f;
                float q1 = d1 * d1;
                float e1 = __expf(-100.0f * q1);
                splitb(e1, h, l);       Th1[kk] = h; Tl1[kk] = l;
                splitb(e1 * q1, h, l);  Dh1[kk] = h; Dl1[kk] = l;
            } else {
                Th1[kk] = 0; Tl1[kk] = 0; Dh1[kk] = 0; Dl1[kk] = 0;
            }
        }
    }

    // ---- init LDS via short8 chunks: 9 chunks/row; 0..5 body, 6..8 K-pad ----
    if (t < 432) {
        const short8 zer  = {0, 0, 0, 0, 0, 0, 0, 0};
        const short  o    = (short)0x3F80;
        const short8 ones = {o, o, o, o, o, o, o, o};
        int ccol = t % 9;
        ((short8*)sW)[t] = (ccol < 6) ? ones : zer;   // W = exp(v/eps) = 1
        if (ccol >= 6) {                               // pads only; body is
            ((short8*)sP )[t] = zer;                   // overwritten pre-read
            ((short8*)sP2)[t] = zer;
        }
    }

    // ---- masses at slots (c, r0+rg) ----
    float mx[4], my[4];
#pragma unroll
    for (int rg = 0; rg < 4; ++rg) {
        mx[rg] = fminf(fmaxf(y4[rg],  0.f), 1e9f) + 1e-9f;
        my[rg] = fminf(fmaxf(yt4[rg], 0.f), 1e9f) + 1e-9f;
    }
    float sx = mx[0] + mx[1] + mx[2] + mx[3];
    float sy = my[0] + my[1] + my[2] + my[3];
#pragma unroll
    for (int off = 32; off > 0; off >>= 1) {
        sx += __shfl_down(sx, off);
        sy += __shfl_down(sy, off);
    }
    if (lane == 0) { red[wid] = sx; red[16 + wid] = sy; }
    __syncthreads();   // also covers LDS init above
    float ax = 0.f, ay = 0.f;
#pragma unroll
    for (int w = 0; w < TPB / 64; ++w) { ax += red[w]; ay += red[16 + w]; }
    const float rsx = 1.0f / ax, rsy = 1.0f / ay;

    float mu_[4], nu_[4];
#pragma unroll
    for (int q = 0; q < 4; ++q) { mu_[q] = mx[q] * rsx; nu_[q] = my[q] * rsy; }

    float wu_[4] = {1, 1, 1, 1}, wv_[4] = {1, 1, 1, 1};  // exp(u/eps), exp(v/eps)

    const f32x4 zz = {0.f, 0.f, 0.f, 0.f};

    // ---- 10 half-iterations: u-update (even) / v-update (odd) ----
    for (int half = 0; half < 10; ++half) {
        // stage 1: D1 = W @ T; store D1^T (b64)
        {
            short8 a0 = *(const short8*)(sW + aBase + kq);
            short8 a1 = *(const short8*)(sW + aBase + kq + 32);
            f32x4 x  = mm16(a0, Th0, zz);
            f32x4 yy = mm16(a1, Th1, zz);
            x  = mm16(a0, Tl0, x);
            yy = mm16(a1, Tl1, yy);
            f32x4 p = x + yy;
            short4v pk;
#pragma unroll
            for (int rg = 0; rg < 4; ++rg) pk[rg] = bf16rne(p[rg]);
            *(short4v*)(sP + stBase) = pk;
        }
        __syncthreads();
        // stage 2: D2 = (D1^T) @ T = S^T at slots; update state; store W' (b64)
        {
            short8 a0 = *(const short8*)(sP + aBase + kq);
            short8 a1 = *(const short8*)(sP + aBase + kq + 32);
            f32x4 x  = mm16(a0, Th0, zz);
            f32x4 yy = mm16(a1, Th1, zz);
            x  = mm16(a0, Tl0, x);
            yy = mm16(a1, Tl1, yy);
            f32x4 S = x + yy;          // S at logical (c, r0+rg)
            float* wc       = ((half & 1) == 0) ? wu_ : wv_;
            const float* m_ = ((half & 1) == 0) ? mu_ : nu_;
            short4v wk;
#pragma unroll
            for (int q = 0; q < 4; ++q) {
                // 100*eps == 1:  w' = e^{u'/eps} = w * mu / (w*S + 1e-6)
                wc[q] = wc[q] * m_[q] / (wc[q] * S[q] + 1e-6f);
                wk[q] = bf16rne(wc[q]);
            }
            *(short4v*)(sW + stBase) = wk;
        }
        __syncthreads();
    }

    // ---- final cost: G = TD@Wv@T + T@Wv@TD, cost = sum wu .* G ----
    {
        short8 a0 = *(const short8*)(sW + aBase + kq);
        short8 a1 = *(const short8*)(sW + aBase + kq + 32);
        f32x4 x1 = mm16(a0, Th0, zz), w1 = mm16(a1, Th1, zz);
        x1 = mm16(a0, Tl0, x1);  w1 = mm16(a1, Tl1, w1);
        f32x4 p1 = x1 + w1;                       // Wv @ T
        f32x4 x2 = mm16(a0, Dh0, zz), w2 = mm16(a1, Dh1, zz);
        x2 = mm16(a0, Dl0, x2);  w2 = mm16(a1, Dl1, w2);
        f32x4 p2 = x2 + w2;                       // Wv @ TD
        short4v k1, k2;
#pragma unroll
        for (int rg = 0; rg < 4; ++rg) { k1[rg] = bf16rne(p1[rg]); k2[rg] = bf16rne(p2[rg]); }
        *(short4v*)(sP  + stBase) = k1;
        *(short4v*)(sP2 + stBase) = k2;
    }
    __syncthreads();
    float local;
    {
        short8 a0 = *(const short8*)(sP  + aBase + kq);
        short8 a1 = *(const short8*)(sP  + aBase + kq + 32);
        short8 c0 = *(const short8*)(sP2 + aBase + kq);
        short8 c1 = *(const short8*)(sP2 + aBase + kq + 32);
        f32x4 x  = mm16(a0, Dh0, zz), yy = mm16(a1, Dh1, zz);
        x  = mm16(a0, Dl0, x);   yy = mm16(a1, Dl1, yy);
        x  = mm16(c0, Th0, x);   yy = mm16(c1, Th1, yy);
        x  = mm16(c0, Tl0, x);   yy = mm16(c1, Tl1, yy);
        f32x4 G = x + yy;          // G at logical (c, r0+rg)
        local = wu_[0] * G[0] + wu_[1] * G[1] + wu_[2] * G[2] + wu_[3] * G[3];
    }
#pragma unroll
    for (int off = 32; off > 0; off >>= 1) local += __shfl_down(local, off);
    if (lane == 0) red[wid] = local;
    __syncthreads();
    float total = 0.f;
#pragma unroll
    for (int w = 0; w < TPB / 64; ++w) total += red[w];

    // ---- cross-block finish: parallel flag poll in block 0 ----
    if (b != 0) {
        if (t == 0) {
            __hip_atomic_store(&parts[b], total, __ATOMIC_RELAXED,
                               __HIP_MEMORY_SCOPE_AGENT);
            __hip_atomic_store(&flags[b], FLAG_MAGIC, __ATOMIC_RELEASE,
                               __HIP_MEMORY_SCOPE_AGENT);
        }
    } else if (wid == 0) {
        float pv = 0.f;
        if (lane >= 1 && lane < 16) {
            while (__hip_atomic_load(&flags[lane], __ATOMIC_ACQUIRE,
                                     __HIP_MEMORY_SCOPE_AGENT) != FLAG_MAGIC) { }
            pv = __hip_atomic_load(&parts[lane], __ATOMIC_RELAXED,
                                   __HIP_MEMORY_SCOPE_AGENT);
        }
        if (lane == 0) pv = total;
#pragma unroll
        for (int off = 8; off > 0; off >>= 1) pv += __shfl_down(pv, off);
        if (lane == 0) out[0] = pv * (1.0f / 16.0f);
    }
}

extern "C" void kernel_launch(void* const* d_in, const int* in_sizes, int n_in,
                              void* d_out, int out_size, void* d_ws, size_t ws_size,
                              hipStream_t stream)
{
    (void)in_sizes; (void)n_in; (void)ws_size; (void)out_size;
    const float* y  = (const float*)d_in[0];
    const float* yt = (const float*)d_in[1];
    unsigned* flags = (unsigned*)d_ws;             // ws[0..15]  (0xAA-poisoned)
    float*    parts = (float*)d_ws + 16;           // ws[16..31]
    float*    out   = (float*)d_out;

    sinkhorn_kernel<<<16, TPB, 0, stream>>>(y, yt, flags, parts, out);
}